// Round 16
// baseline (2150.772 us; speedup 1.0000x reference)
//
#include <hip/hip_runtime.h>
#include <hip/hip_fp16.h>

// Problem sizes
#define B_SZ 32
#define L_SZ 512
#define D_SZ 1024
#define H_SZ 1024
#define NG   4096           // 4*H
#define M_SZ 16384          // B*L

typedef __attribute__((ext_vector_type(8))) short short8;
typedef __attribute__((ext_vector_type(4))) float f32x4;
typedef __attribute__((ext_vector_type(4))) unsigned u32x4;
typedef __attribute__((ext_vector_type(4))) unsigned short u16x4;

// Workspace layout (bytes). Total ~184.7 MB.
// XB region doubles as the h RING (512 slots x 64 KB = exactly 32 MiB) once
// k_xgemm has consumed the bf16 x data.
static const size_t GX_OFF  = 0;                  // Gx fp16: 16384*4096*2 = 134217728
static const size_t XB_OFF  = 134217728;          // x bf16 / h ring: 33554432
static const size_t WH_OFF  = 167772160;          // Wh bf16: 8388608
static const size_t WX_OFF  = 176160768;          // Wx bf16: 8388608
static const size_t FLG_OFF = 184680448;          // flags: 128 WGs x 64B (4 dwords used)

__device__ __forceinline__ unsigned short f2bf(float f) {
  union { float f; unsigned u; } v; v.f = f;
  unsigned r = v.u + 0x7fffu + ((v.u >> 16) & 1u);
  return (unsigned short)(r >> 16);
}

// fast gating math: __expf -> v_exp_f32 (~1e-6 rel err vs 3.9e-3 bf16 floor).
// ftanh clamps to +-15 to avoid exp overflow->NaN.
__device__ __forceinline__ float fsig(float x) { return 1.f / (1.f + __expf(-x)); }
__device__ __forceinline__ float ftanh(float x) {
  x = fminf(fmaxf(x, -15.f), 15.f);
  float e = __expf(-2.f * x);
  return (1.f - e) / (1.f + e);
}

__device__ __forceinline__ void gload_lds16(const void* g, void* l) {
  __builtin_amdgcn_global_load_lds(
      (const __attribute__((address_space(1))) unsigned*)g,
      (__attribute__((address_space(3))) unsigned*)l, 16, 0, 0);
}

// ---- prep kernels -----------------------------------------------------------

__global__ __launch_bounds__(256) void k_convert_w(const float* __restrict__ W,
                                                   unsigned short* __restrict__ Wh,
                                                   unsigned short* __restrict__ Wx) {
  int idx = blockIdx.x * 256 + threadIdx.x;          // 4096*2048/4 = 2097152 total
  f32x4 v = ((const f32x4*)W)[idx];
  u16x4 o;
#pragma unroll
  for (int e = 0; e < 4; ++e) o[e] = f2bf(v[e]);
  int n   = idx >> 9;                                // 512 float4 per 2048-col row
  int col = (idx & 511) * 4;
  if (col < 1024) *(u16x4*)(Wh + (size_t)n * 1024 + col)          = o;
  else            *(u16x4*)(Wx + (size_t)n * 1024 + (col - 1024)) = o;
}

// xb region later becomes the h ring, written sc0sc1 (write-through). xb is
// also stored write-through so NO dirty L2 line of this region can ever be
// written back late and clobber ring data.
__global__ __launch_bounds__(256) void k_convert_x(const float* __restrict__ x,
                                                   unsigned short* __restrict__ xb) {
  int idx = blockIdx.x * 256 + threadIdx.x;          // 16777216/4 = 4194304 total
  f32x4 v = ((const f32x4*)x)[idx];
  u16x4 o;
#pragma unroll
  for (int e = 0; e < 4; ++e) o[e] = f2bf(v[e]);
  unsigned long long val;
  __builtin_memcpy(&val, &o, 8);
  unsigned short* p = xb + (size_t)idx * 4;
  asm volatile("global_store_dwordx2 %0, %1, off sc0 sc1"
               :: "v"(p), "v"(val) : "memory");
}

__global__ __launch_bounds__(256) void k_zero_wt(unsigned* __restrict__ p, int n) {
  int i = blockIdx.x * 256 + threadIdx.x;
  unsigned z = 0u;
  if (i < n)
    asm volatile("global_store_dword %0, %1, off sc0 sc1"
                 :: "v"(p + i), "v"(z) : "memory");
}

// ---- x-projection GEMM: Gx[m][n] = sum_d x[m][d] * Wx[n][d] (fp16 out) ------

__global__ __launch_bounds__(256) void k_xgemm(const unsigned short* __restrict__ A,
                                               const unsigned short* __restrict__ Bw,
                                               __half* __restrict__ C) {
  __shared__ unsigned short sA[128 * 64];
  __shared__ unsigned short sB[128 * 64];
  const int m0 = blockIdx.x * 128;
  const int n0 = blockIdx.y * 128;
  const int tid = threadIdx.x;
  const int lane = tid & 63;
  const int w = tid >> 6;
  const int wm = w >> 1, wn = w & 1;
  f32x4 acc[4][4] = {};
  for (int k0 = 0; k0 < 1024; k0 += 64) {
#pragma unroll
    for (int it = 0; it < 4; ++it) {
      int chunk = it * 256 + w * 64 + lane;
      int row = chunk >> 3, kc = chunk & 7;
      gload_lds16(A + (size_t)(m0 + row) * 1024 + k0 + kc * 8,
                  (char*)sA + (size_t)(it * 256 + w * 64) * 16);
      gload_lds16(Bw + (size_t)(n0 + row) * 1024 + k0 + kc * 8,
                  (char*)sB + (size_t)(it * 256 + w * 64) * 16);
    }
    asm volatile("s_waitcnt vmcnt(0)" ::: "memory");
    __syncthreads();
#pragma unroll
    for (int ks = 0; ks < 2; ++ks) {
      short8 af[4], bfr[4];
#pragma unroll
      for (int i = 0; i < 4; ++i) {
        int arow = wm * 64 + i * 16 + (lane & 15);
        af[i] = *(const short8*)(sA + arow * 64 + ks * 32 + (lane >> 4) * 8);
      }
#pragma unroll
      for (int j = 0; j < 4; ++j) {
        int brow = wn * 64 + j * 16 + (lane & 15);
        bfr[j] = *(const short8*)(sB + brow * 64 + ks * 32 + (lane >> 4) * 8);
      }
#pragma unroll
      for (int i = 0; i < 4; ++i)
#pragma unroll
        for (int j = 0; j < 4; ++j)
          acc[i][j] = __builtin_amdgcn_mfma_f32_16x16x32_bf16(af[i], bfr[j], acc[i][j], 0, 0, 0);
    }
    __syncthreads();
  }
#pragma unroll
  for (int i = 0; i < 4; ++i)
#pragma unroll
    for (int j = 0; j < 4; ++j)
#pragma unroll
      for (int q = 0; q < 4; ++q) {
        int row = m0 + wm * 64 + i * 16 + (lane >> 4) * 4 + q;
        int col = n0 + wn * 64 + j * 16 + (lane & 15);
        C[(size_t)row * NG + col] = __float2half(acc[i][j][q]);
      }
}

// ---- persistent recurrent kernel -------------------------------------------
// 128 WGs x 256 threads (1 WG/CU). WG wg owns hidden j0..j0+7 across all 4
// gates. K-SPLIT: wave wv owns K-slice [wv*256,+256) (produced by WGs
// [wv*32,+32)), computes all four 16x16 quadrants; Wh B-frags in registers;
// partials via DOUBLE-BUFFERED fp32 part[2][4][32][36] in LDS.
//
// R15 tail: per-wave, shfl-free, barrier-free. hlds is WAVE-PRIVATE
// (wave wv's lanes write hlds[wv*64..+63]; its lanes 0-7 read them back
// with one ds_read_b128 - same-wave DS pipe is in-order, lgkmcnt guarded).
// So sync2 is DELETED. The part WAR that sync2 also guarded is fixed by
// double-buffering part: reads(t) precede sync1(t+1) in program order,
// writes(t+2) follow it -> barrier-ordered, no timing-margin race. Each
// wave stores its own 8 batches (8 x 16B sc0sc1), drains, raises its OWN
// flag dword (4 dwords per producer-WG 64B line), then goes straight to
// the next step's poll. `out` store issued BEFORE the drain so its ack
// overlaps the h-store drain (R14's regression: out after flag made the
// next poll's vmcnt(0) eat the scattered-store ack).
//
// Poll: single-buffered dwordx4 + vmcnt(0) in-loop (R13 lesson: never leave
// an in-flight load whose dest VGPRs may be recycled). One load checks all
// 4 wave-flags of a producer WG.
//
// RULE #18: every asm-load result consumed by register-only ops is guarded
// by s_waitcnt + sched_barrier(0).
//
// Cross-step h exchange (proven): 512-slot ring; producers store slot t+1
// sc0 sc1 (write-through; own-wave vmcnt(0) ack precedes own flag).
// Consumers poll flags sc0sc1, then DMA slot t with normal cached loads
// (virgin lines; kernel-start acquire fence drops stale clean copies).

__global__ __launch_bounds__(256, 1) void k_lstm(const unsigned short* __restrict__ Whg,
                                                 const __half* __restrict__ Gx,
                                                 const float* __restrict__ bias,
                                                 unsigned short* __restrict__ ring,
                                                 float* __restrict__ out,
                                                 unsigned* __restrict__ flags) {
  extern __shared__ char lds[];
  char* h2      = lds;                                 // [4][32][512B] = 65536
  float* part   = (float*)(lds + 65536);               // [2][4][32][36] = 36864
  float* bias_s = (float*)(lds + 65536 + 36864);       // [32]
  unsigned short* hlds = (unsigned short*)(lds + 65536 + 36864 + 128); // [256]

  const int tid = threadIdx.x;
  const int lane = tid & 63;
  const int wv = tid >> 6;          // wave id = K-slice owner
  const int wg = blockIdx.x;
  const int j0 = wg * 8;

  // acquire: drop stale clean cached lines of the ring region before any
  // cached ring read in this launch.
  __builtin_amdgcn_fence(__ATOMIC_ACQUIRE, "agent");

  // ---- one-time: this wave's K-slice of Wh -> registers (16 frags) ----
  short8 bfrag[2][8];
#pragma unroll
  for (int ntx = 0; ntx < 2; ++ntx) {
#pragma unroll
    for (int ks = 0; ks < 8; ++ks) {
      int br = ntx * 16 + (lane & 15);                 // local gate col
      const unsigned short* src = Whg
          + (size_t)((br >> 3) * 1024 + j0 + (br & 7)) * 1024
          + wv * 256 + ks * 32 + (lane >> 4) * 8;
      bfrag[ntx][ks] = *(const short8*)src;
    }
  }
  if (tid < 32) bias_s[tid] = bias[(tid >> 3) * 1024 + j0 + (tid & 7)];
  __syncthreads();

  const int r0 = lane & 15;                            // A rows; second half +16
  char* aSlice = h2 + wv * 16384;
  const int kcl = lane >> 4;                           // 16B sub-slot within 64B chunk
  const int b_ = tid >> 3, jj = tid & 7;
  const float rb0 = bias_s[jj], rb1 = bias_s[8 + jj];
  const float rb2 = bias_s[16 + jj], rb3 = bias_s[24 + jj];
  float c_reg = 0.f;                                   // cell state (thread-private)

  // per-wave poll pointer: wave wv polls flag lines of WGs [wv*32, wv*32+32);
  // each 64B line's dwords 0..3 are that WG's four wave-flags.
  const unsigned* myfp = flags + (size_t)(wv * 32 + (lane & 31)) * 16;

  for (int t = 0; t < 512; ++t) {
    const char* hin = (const char*)ring + (size_t)t * 65536;   // slot t
    unsigned short* hout = ring + (size_t)(t + 1) * 32768;     // slot t+1
    float* partc = part + (t & 1) * 4608;                      // current part buffer

    // ---- issue Gx loads (cached; drained by the poll/DMA vmcnt below) ----
    const char* gxp = (const char*)(Gx + ((size_t)(b_ * L_SZ + t)) * NG + j0 + jj);
    unsigned gxa, gxb, gxc, gxd;
    asm volatile("global_load_ushort %0, %1, off" : "=v"(gxa) : "v"(gxp)        : "memory");
    asm volatile("global_load_ushort %0, %1, off" : "=v"(gxb) : "v"(gxp + 2048) : "memory");
    asm volatile("global_load_ushort %0, %1, off" : "=v"(gxc) : "v"(gxp + 4096) : "memory");
    asm volatile("global_load_ushort %0, %1, off" : "=v"(gxd) : "v"(gxp + 6144) : "memory");

    if (t) {
      // ---- single-buffered per-wave poll: one dwordx4 = all 4 wave-flags ----
      const unsigned tt = (unsigned)t;
      u32x4 fA;
      do {
        asm volatile("global_load_dwordx4 %0, %1, off sc0 sc1\n\t"
                     "s_waitcnt vmcnt(0)"
                     : "=v"(fA) : "v"(myfp) : "memory");
        __builtin_amdgcn_sched_barrier(0);             // rule #18
      } while (!__all(fA[0] >= tt && fA[1] >= tt && fA[2] >= tt && fA[3] >= tt));
      // ---- DMA my 16 KB slice into h2[wv] (swizzled global source) ----
#pragma unroll
      for (int j = 0; j < 16; ++j) {
        int s = j * 64 + lane;                         // slot in my slice
        int row = s >> 5, kc = s & 31;                 // row 0..31, 16B unit 0..31
        const char* src = hin + row * 2048 + wv * 512 + ((kc ^ (row & 7)) << 4);
        gload_lds16(src, aSlice + j * 1024);           // wave-uniform LDS base
      }
      asm volatile("s_waitcnt vmcnt(0)" ::: "memory"); // slice landed (Gx already)
      __builtin_amdgcn_sched_barrier(0);               // rule #18 fence
    } else {
      u32x4 z = {0u, 0u, 0u, 0u};
#pragma unroll
      for (int j = 0; j < 16; ++j)
        *(u32x4*)(aSlice + j * 1024 + lane * 16) = z;
      asm volatile("s_waitcnt vmcnt(0)" ::: "memory"); // Gx landed
      __builtin_amdgcn_sched_barrier(0);               // rule #18 fence
    }

    // ---- K-split MFMA: all 4 quadrants over my slice (no staging sync) ----
    f32x4 acc00 = {0.f,0.f,0.f,0.f}, acc01 = {0.f,0.f,0.f,0.f};
    f32x4 acc10 = {0.f,0.f,0.f,0.f}, acc11 = {0.f,0.f,0.f,0.f};
#pragma unroll
    for (int ks = 0; ks < 8; ++ks) {
      int kc = ks * 4 + kcl;
      int off = (kc ^ (r0 & 7)) << 4;                  // (16+r0)&7 == r0&7
      short8 a0 = *(const short8*)(aSlice + r0 * 512 + off);
      short8 a1 = *(const short8*)(aSlice + (16 + r0) * 512 + off);
      acc00 = __builtin_amdgcn_mfma_f32_16x16x32_bf16(a0, bfrag[0][ks], acc00, 0, 0, 0);
      acc01 = __builtin_amdgcn_mfma_f32_16x16x32_bf16(a0, bfrag[1][ks], acc01, 0, 0, 0);
      acc10 = __builtin_amdgcn_mfma_f32_16x16x32_bf16(a1, bfrag[0][ks], acc10, 0, 0, 0);
      acc11 = __builtin_amdgcn_mfma_f32_16x16x32_bf16(a1, bfrag[1][ks], acc11, 0, 0, 0);
    }
    // partial store: partc[wv][row][col], stride 36
    {
      float* pw = partc + wv * 1152;
      int pr0 = (lane >> 4) * 4, cA = lane & 15;
#pragma unroll
      for (int q = 0; q < 4; ++q) {
        pw[(pr0 + q) * 36 + cA]           = acc00[q];
        pw[(pr0 + q) * 36 + 16 + cA]      = acc01[q];
        pw[(16 + pr0 + q) * 36 + cA]      = acc10[q];
        pw[(16 + pr0 + q) * 36 + 16 + cA] = acc11[q];
      }
    }
    __syncthreads();                                   // sync1: exchange

    // ---- gating: sum 4 partials, thread -> (batch b_, hidden j0+jj) ----
    float s0 = 0.f, s1 = 0.f, s2 = 0.f, s3 = 0.f;
#pragma unroll
    for (int p = 0; p < 4; ++p) {
      const float* pp = partc + p * 1152 + b_ * 36 + jj;
      s0 += pp[0]; s1 += pp[8]; s2 += pp[16]; s3 += pp[24];
    }
    float hn;
    {
      float sf = s0 + __half2float(__ushort_as_half((unsigned short)gxa)) + rb0;
      float si = s1 + __half2float(__ushort_as_half((unsigned short)gxb)) + rb1;
      float so = s2 + __half2float(__ushort_as_half((unsigned short)gxc)) + rb2;
      float sc = s3 + __half2float(__ushort_as_half((unsigned short)gxd)) + rb3;
      float cn = fsig(sf) * c_reg + fsig(si) * ftanh(sc);
      hn = fsig(so) * ftanh(cn);
      c_reg = cn;
      hlds[tid] = f2bf(hn);                            // wave-private region of hlds
    }
    out[((size_t)b_ * L_SZ + t) * H_SZ + j0 + jj] = hn; // issued early; ack overlaps drain

    // ---- per-wave tail: LDS-read own 8 batches, store, drain, own flag ----
    // (no barrier: hlds[wv*64..+63] written & read by wave wv only; DS pipe
    //  is in-order per wave, lgkmcnt guards the read)
    if (t < 511) {
      asm volatile("s_waitcnt lgkmcnt(0)" ::: "memory");
      __builtin_amdgcn_sched_barrier(0);               // rule #18 (ds ordering)
      if (lane < 8) {                                  // my wave's batch (wv*8+lane)
        u32x4 pv = *(u32x4*)(hlds + wv * 64 + lane * 8);
        unsigned short* hp = hout + (size_t)(wv * 8 + lane) * H_SZ + j0;
        asm volatile("global_store_dwordx4 %0, %1, off sc0 sc1"
                     :: "v"(hp), "v"(pv) : "memory");
      }
      asm volatile("s_waitcnt vmcnt(0)" ::: "memory"); // own h (+out) stores at CP
      if (lane == 0) {                                 // own flag dword
        unsigned fv = (unsigned)(t + 1);
        const unsigned* myf = flags + (size_t)wg * 16 + wv;
        asm volatile("global_store_dword %0, %1, off sc0 sc1"
                     :: "v"(myf), "v"(fv) : "memory");
      }
    }
  }
}

// ---- host launcher ----------------------------------------------------------

extern "C" void kernel_launch(void* const* d_in, const int* in_sizes, int n_in,
                              void* d_out, int out_size, void* d_ws, size_t ws_size,
                              hipStream_t stream) {
  const float* x = (const float*)d_in[0];
  const float* W = (const float*)d_in[1];
  const float* b = (const float*)d_in[2];
  char* ws = (char*)d_ws;
  __half* Gx           = (__half*)(ws + GX_OFF);
  unsigned short* xb   = (unsigned short*)(ws + XB_OFF);   // becomes h ring
  unsigned short* Wh   = (unsigned short*)(ws + WH_OFF);
  unsigned short* Wx   = (unsigned short*)(ws + WX_OFF);
  unsigned* flags      = (unsigned*)(ws + FLG_OFF);
  float* out = (float*)d_out;

  // prep: bf16 conversions + zero flags (re-zeroed every call -> deterministic)
  k_convert_w<<<8192, 256, 0, stream>>>(W, Wh, Wx);
  k_convert_x<<<16384, 256, 0, stream>>>(x, xb);
  k_zero_wt<<<8, 256, 0, stream>>>(flags, 2048);

  // input projection for all timesteps (consumes xb)
  k_xgemm<<<dim3(128, 32), 256, 0, stream>>>(xb, Wx, Gx);

  // persistent recurrence (103040 B dynamic LDS > 64KB default -> raise cap)
  (void)hipFuncSetAttribute((const void*)k_lstm,
                            hipFuncAttributeMaxDynamicSharedMemorySize, 103040);
  k_lstm<<<128, 256, 103040, stream>>>(Wh, Gx, b, xb, out, flags);
}

// Round 17
// 1949.870 us; speedup vs baseline: 1.1030x; 1.1030x over previous
//
#include <hip/hip_runtime.h>
#include <hip/hip_fp16.h>

// Problem sizes
#define B_SZ 32
#define L_SZ 512
#define D_SZ 1024
#define H_SZ 1024
#define NG   4096           // 4*H
#define M_SZ 16384          // B*L

typedef __attribute__((ext_vector_type(8))) short short8;
typedef __attribute__((ext_vector_type(4))) float f32x4;
typedef __attribute__((ext_vector_type(4))) unsigned u32x4;
typedef __attribute__((ext_vector_type(4))) unsigned short u16x4;

// Workspace layout (bytes). Total ~184.7 MB.
// XB region doubles as the h RING (512 slots x 64 KB = exactly 32 MiB) once
// k_xgemm has consumed the bf16 x data.
static const size_t GX_OFF  = 0;                  // Gx fp16: 16384*4096*2 = 134217728
static const size_t XB_OFF  = 134217728;          // x bf16 / h ring: 33554432
static const size_t WH_OFF  = 167772160;          // Wh bf16: 8388608
static const size_t WX_OFF  = 176160768;          // Wx bf16: 8388608
static const size_t FLG_OFF = 184680448;          // flags: 128 x 64B = 8192

__device__ __forceinline__ unsigned short f2bf(float f) {
  union { float f; unsigned u; } v; v.f = f;
  unsigned r = v.u + 0x7fffu + ((v.u >> 16) & 1u);
  return (unsigned short)(r >> 16);
}

// fast gating math: __expf -> v_exp_f32 (~1e-6 rel err vs 3.9e-3 bf16 floor).
// ftanh clamps to +-15 to avoid exp overflow->NaN.
__device__ __forceinline__ float fsig(float x) { return 1.f / (1.f + __expf(-x)); }
__device__ __forceinline__ float ftanh(float x) {
  x = fminf(fmaxf(x, -15.f), 15.f);
  float e = __expf(-2.f * x);
  return (1.f - e) / (1.f + e);
}

__device__ __forceinline__ void gload_lds16(const void* g, void* l) {
  __builtin_amdgcn_global_load_lds(
      (const __attribute__((address_space(1))) unsigned*)g,
      (__attribute__((address_space(3))) unsigned*)l, 16, 0, 0);
}

// ---- prep kernels -----------------------------------------------------------

__global__ __launch_bounds__(256) void k_convert_w(const float* __restrict__ W,
                                                   unsigned short* __restrict__ Wh,
                                                   unsigned short* __restrict__ Wx) {
  int idx = blockIdx.x * 256 + threadIdx.x;          // 4096*2048/4 = 2097152 total
  f32x4 v = ((const f32x4*)W)[idx];
  u16x4 o;
#pragma unroll
  for (int e = 0; e < 4; ++e) o[e] = f2bf(v[e]);
  int n   = idx >> 9;                                // 512 float4 per 2048-col row
  int col = (idx & 511) * 4;
  if (col < 1024) *(u16x4*)(Wh + (size_t)n * 1024 + col)          = o;
  else            *(u16x4*)(Wx + (size_t)n * 1024 + (col - 1024)) = o;
}

// xb region later becomes the h ring, written sc0sc1 (write-through). xb is
// also stored write-through so NO dirty L2 line of this region can ever be
// written back late and clobber ring data.
__global__ __launch_bounds__(256) void k_convert_x(const float* __restrict__ x,
                                                   unsigned short* __restrict__ xb) {
  int idx = blockIdx.x * 256 + threadIdx.x;          // 16777216/4 = 4194304 total
  f32x4 v = ((const f32x4*)x)[idx];
  u16x4 o;
#pragma unroll
  for (int e = 0; e < 4; ++e) o[e] = f2bf(v[e]);
  unsigned long long val;
  __builtin_memcpy(&val, &o, 8);
  unsigned short* p = xb + (size_t)idx * 4;
  asm volatile("global_store_dwordx2 %0, %1, off sc0 sc1"
               :: "v"(p), "v"(val) : "memory");
}

__global__ __launch_bounds__(256) void k_zero_wt(unsigned* __restrict__ p, int n) {
  int i = blockIdx.x * 256 + threadIdx.x;
  unsigned z = 0u;
  if (i < n)
    asm volatile("global_store_dword %0, %1, off sc0 sc1"
                 :: "v"(p + i), "v"(z) : "memory");
}

// ---- x-projection GEMM: Gx[m][n] = sum_d x[m][d] * Wx[n][d] (fp16 out) ------
// m97 structure + XCD-aware bijective block swizzle (T1; nwg=4096, %8==0).

__global__ __launch_bounds__(256) void k_xgemm(const unsigned short* __restrict__ A,
                                               const unsigned short* __restrict__ Bw,
                                               __half* __restrict__ C) {
  __shared__ unsigned short sA[128 * 64];
  __shared__ unsigned short sB[128 * 64];
  // XCD swizzle: dispatch-linear id -> contiguous chunk per XCD
  int orig = blockIdx.y * gridDim.x + blockIdx.x;    // 0..4095, x-fastest dispatch
  int swz  = (orig & 7) * 512 + (orig >> 3);         // bijective (4096 = 8*512)
  const int m0 = (swz & 127) * 128;
  const int n0 = (swz >> 7) * 128;
  const int tid = threadIdx.x;
  const int lane = tid & 63;
  const int w = tid >> 6;
  const int wm = w >> 1, wn = w & 1;
  f32x4 acc[4][4] = {};
  for (int k0 = 0; k0 < 1024; k0 += 64) {
#pragma unroll
    for (int it = 0; it < 4; ++it) {
      int chunk = it * 256 + w * 64 + lane;
      int row = chunk >> 3, kc = chunk & 7;
      gload_lds16(A + (size_t)(m0 + row) * 1024 + k0 + kc * 8,
                  (char*)sA + (size_t)(it * 256 + w * 64) * 16);
      gload_lds16(Bw + (size_t)(n0 + row) * 1024 + k0 + kc * 8,
                  (char*)sB + (size_t)(it * 256 + w * 64) * 16);
    }
    asm volatile("s_waitcnt vmcnt(0)" ::: "memory");
    __syncthreads();
#pragma unroll
    for (int ks = 0; ks < 2; ++ks) {
      short8 af[4], bfr[4];
#pragma unroll
      for (int i = 0; i < 4; ++i) {
        int arow = wm * 64 + i * 16 + (lane & 15);
        af[i] = *(const short8*)(sA + arow * 64 + ks * 32 + (lane >> 4) * 8);
      }
#pragma unroll
      for (int j = 0; j < 4; ++j) {
        int brow = wn * 64 + j * 16 + (lane & 15);
        bfr[j] = *(const short8*)(sB + brow * 64 + ks * 32 + (lane >> 4) * 8);
      }
#pragma unroll
      for (int i = 0; i < 4; ++i)
#pragma unroll
        for (int j = 0; j < 4; ++j)
          acc[i][j] = __builtin_amdgcn_mfma_f32_16x16x32_bf16(af[i], bfr[j], acc[i][j], 0, 0, 0);
    }
    __syncthreads();
  }
#pragma unroll
  for (int i = 0; i < 4; ++i)
#pragma unroll
    for (int j = 0; j < 4; ++j)
#pragma unroll
      for (int q = 0; q < 4; ++q) {
        int row = m0 + wm * 64 + i * 16 + (lane >> 4) * 4 + q;
        int col = n0 + wn * 64 + j * 16 + (lane & 15);
        C[(size_t)row * NG + col] = __float2half(acc[i][j][q]);
      }
}

// ---- persistent recurrent kernel (R12-proven structure, verbatim) -----------
// 128 WGs x 256 threads (1 WG/CU). WG wg owns hidden j0..j0+7 across all 4
// gates. K-SPLIT: wave wv owns K-slice [wv*256,+256) (produced by WGs
// [wv*32,+32)), computes all four 16x16 quadrants; Wh B-frags in registers;
// partials via fp32 part[4][32][36] in LDS.
//
// PER-WAVE DECOUPLED STEP: each wave polls ONLY its 32 producer flags, DMAs
// ONLY its own 16 KB LDS slice h2[wv][32][512B] (swizzled global source,
// rule #21 involution), and proceeds to MFMA with no staging sync. Tail is
// wave-parallel: wave 1 packs/stores h + drains + raises the flag while
// waves 0/2/3 move straight to the next step's poll. TWO __syncthreads per
// step. Hazards: part(t+1) writes ordered after part(t) reads by the
// hlds-sync; hlds(t+1) writes ordered after wave-1's hlds(t) reads by the
// exchange-sync of t+1; ring slots step-disjoint; flags monotonic.
//
// Cross-step h exchange: 512-slot ring; producers store slot t+1 sc0 sc1
// (write-through; wave-1 vmcnt(0) ack precedes the flag). Consumers poll
// flags sc0sc1, then DMA slot t with normal cached loads (virgin lines;
// kernel-start acquire fence drops stale clean copies).

__global__ __launch_bounds__(256, 1) void k_lstm(const unsigned short* __restrict__ Whg,
                                                 const __half* __restrict__ Gx,
                                                 const float* __restrict__ bias,
                                                 unsigned short* __restrict__ ring,
                                                 float* __restrict__ out,
                                                 unsigned* __restrict__ flags) {
  extern __shared__ char lds[];
  char* h2      = lds;                                 // [4][32][512B] = 65536
  float* part   = (float*)(lds + 65536);               // [4][32][36] fp32 = 18432
  float* bias_s = (float*)(lds + 83968);               // [32]
  unsigned short* hlds = (unsigned short*)(lds + 84096); // [256]

  const int tid = threadIdx.x;
  const int lane = tid & 63;
  const int wv = tid >> 6;          // wave id = K-slice owner
  const int wg = blockIdx.x;
  const int j0 = wg * 8;

  // acquire: drop stale clean cached lines of the ring region before any
  // cached ring read in this launch.
  __builtin_amdgcn_fence(__ATOMIC_ACQUIRE, "agent");

  // ---- one-time: this wave's K-slice of Wh -> registers (16 frags) ----
  short8 bfrag[2][8];
#pragma unroll
  for (int ntx = 0; ntx < 2; ++ntx) {
#pragma unroll
    for (int ks = 0; ks < 8; ++ks) {
      int br = ntx * 16 + (lane & 15);                 // local gate col
      const unsigned short* src = Whg
          + (size_t)((br >> 3) * 1024 + j0 + (br & 7)) * 1024
          + wv * 256 + ks * 32 + (lane >> 4) * 8;
      bfrag[ntx][ks] = *(const short8*)src;
    }
  }
  if (tid < 32) bias_s[tid] = bias[(tid >> 3) * 1024 + j0 + (tid & 7)];
  __syncthreads();

  const int r0 = lane & 15;                            // A rows; second half +16
  char* aSlice = h2 + wv * 16384;
  const int kcl = lane >> 4;                           // 16B sub-slot within 64B chunk
  const int b_ = tid >> 3, jj = tid & 7;
  const float rb0 = bias_s[jj], rb1 = bias_s[8 + jj];
  const float rb2 = bias_s[16 + jj], rb3 = bias_s[24 + jj];
  float c_reg = 0.f;                                   // cell state (thread-private)

  // per-wave poll pointer: wave wv polls flags of WGs [wv*32, wv*32+32)
  const unsigned* myfp = flags + (size_t)(wv * 32 + (lane & 31)) * 16;

  for (int t = 0; t < 512; ++t) {
    const char* hin = (const char*)ring + (size_t)t * 65536;   // slot t
    unsigned short* hout = ring + (size_t)(t + 1) * 32768;     // slot t+1

    // ---- issue Gx loads (cached; drained by the DMA vmcnt below) ----
    const char* gxp = (const char*)(Gx + ((size_t)(b_ * L_SZ + t)) * NG + j0 + jj);
    unsigned gxa, gxb, gxc, gxd;
    asm volatile("global_load_ushort %0, %1, off" : "=v"(gxa) : "v"(gxp)        : "memory");
    asm volatile("global_load_ushort %0, %1, off" : "=v"(gxb) : "v"(gxp + 2048) : "memory");
    asm volatile("global_load_ushort %0, %1, off" : "=v"(gxc) : "v"(gxp + 4096) : "memory");
    asm volatile("global_load_ushort %0, %1, off" : "=v"(gxd) : "v"(gxp + 6144) : "memory");

    if (t) {
      // ---- per-wave poll: my K-slice's 32 producers (flag >= t) ----
      unsigned fa;
      do {
        asm volatile("global_load_dword %0, %1, off sc0 sc1\n\t"
                     "s_waitcnt vmcnt(0)"
                     : "=v"(fa) : "v"(myfp) : "memory");
      } while (__any(fa < (unsigned)t));
      // ---- DMA my 16 KB slice into h2[wv] (swizzled global source) ----
#pragma unroll
      for (int j = 0; j < 16; ++j) {
        int s = j * 64 + lane;                         // slot in my slice
        int row = s >> 5, kc = s & 31;                 // row 0..31, 16B unit 0..31
        const char* src = hin + row * 2048 + wv * 512 + ((kc ^ (row & 7)) << 4);
        gload_lds16(src, aSlice + j * 1024);           // wave-uniform LDS base
      }
      asm volatile("s_waitcnt vmcnt(0)" ::: "memory"); // slice + Gx landed
      __builtin_amdgcn_sched_barrier(0);               // rule #18 fence
    } else {
      u32x4 z = {0u, 0u, 0u, 0u};
#pragma unroll
      for (int j = 0; j < 16; ++j)
        *(u32x4*)(aSlice + j * 1024 + lane * 16) = z;
      asm volatile("s_waitcnt vmcnt(0)" ::: "memory"); // Gx landed
      __builtin_amdgcn_sched_barrier(0);               // rule #18 fence
    }

    // ---- K-split MFMA: all 4 quadrants over my slice (no staging sync) ----
    f32x4 acc00 = {0.f,0.f,0.f,0.f}, acc01 = {0.f,0.f,0.f,0.f};
    f32x4 acc10 = {0.f,0.f,0.f,0.f}, acc11 = {0.f,0.f,0.f,0.f};
#pragma unroll
    for (int ks = 0; ks < 8; ++ks) {
      int kc = ks * 4 + kcl;
      int off = (kc ^ (r0 & 7)) << 4;                  // (16+r0)&7 == r0&7
      short8 a0 = *(const short8*)(aSlice + r0 * 512 + off);
      short8 a1 = *(const short8*)(aSlice + (16 + r0) * 512 + off);
      acc00 = __builtin_amdgcn_mfma_f32_16x16x32_bf16(a0, bfrag[0][ks], acc00, 0, 0, 0);
      acc01 = __builtin_amdgcn_mfma_f32_16x16x32_bf16(a0, bfrag[1][ks], acc01, 0, 0, 0);
      acc10 = __builtin_amdgcn_mfma_f32_16x16x32_bf16(a1, bfrag[0][ks], acc10, 0, 0, 0);
      acc11 = __builtin_amdgcn_mfma_f32_16x16x32_bf16(a1, bfrag[1][ks], acc11, 0, 0, 0);
    }
    // partial store: part[wv][row][col], stride 36
    {
      float* pw = part + wv * 1152;
      int pr0 = (lane >> 4) * 4, cA = lane & 15;
#pragma unroll
      for (int q = 0; q < 4; ++q) {
        pw[(pr0 + q) * 36 + cA]           = acc00[q];
        pw[(pr0 + q) * 36 + 16 + cA]      = acc01[q];
        pw[(16 + pr0 + q) * 36 + cA]      = acc10[q];
        pw[(16 + pr0 + q) * 36 + 16 + cA] = acc11[q];
      }
    }
    __syncthreads();                                   // sync1: exchange

    // ---- gating: sum 4 partials, thread -> (batch b_, hidden j0+jj) ----
    float s0 = 0.f, s1 = 0.f, s2 = 0.f, s3 = 0.f;
#pragma unroll
    for (int p = 0; p < 4; ++p) {
      const float* pp = part + p * 1152 + b_ * 36 + jj;
      s0 += pp[0]; s1 += pp[8]; s2 += pp[16]; s3 += pp[24];
    }
    float hn;
    {
      float sf = s0 + __half2float(__ushort_as_half((unsigned short)gxa)) + rb0;
      float si = s1 + __half2float(__ushort_as_half((unsigned short)gxb)) + rb1;
      float so = s2 + __half2float(__ushort_as_half((unsigned short)gxc)) + rb2;
      float sc = s3 + __half2float(__ushort_as_half((unsigned short)gxd)) + rb3;
      float cn = fsig(sf) * c_reg + fsig(si) * ftanh(sc);
      hn = fsig(so) * ftanh(cn);
      c_reg = cn;
      hlds[tid] = f2bf(hn);                            // hlds[b_*8+jj] == hlds[tid]
    }
    out[((size_t)b_ * L_SZ + t) * H_SZ + j0 + jj] = hn; // cached, off critical path
    __syncthreads();                                   // sync2: hlds ready

    // ---- wave-parallel tail: wave 1 stores h + flag; others loop to poll ----
    if (t < 511) {
      if (tid >= 64 && tid < 96) {                     // wave 1, lanes 0..31
        int c = tid - 64;
        u32x4 v = *(u32x4*)(hlds + c * 8);
        unsigned short* hp = hout + (size_t)c * H_SZ + j0;
        asm volatile("global_store_dwordx4 %0, %1, off sc0 sc1"
                     :: "v"(hp), "v"(v) : "memory");
      }
      if (wv == 1) {
        asm volatile("s_waitcnt vmcnt(0)" ::: "memory"); // wave-1 stores at CP
        if (tid == 64) {
          unsigned fv = (unsigned)(t + 1);
          const unsigned* myf = flags + (size_t)wg * 16;
          asm volatile("global_store_dword %0, %1, off sc0 sc1"
                       :: "v"(myf), "v"(fv) : "memory");
        }
      }
    }
  }
}

// ---- host launcher ----------------------------------------------------------

extern "C" void kernel_launch(void* const* d_in, const int* in_sizes, int n_in,
                              void* d_out, int out_size, void* d_ws, size_t ws_size,
                              hipStream_t stream) {
  const float* x = (const float*)d_in[0];
  const float* W = (const float*)d_in[1];
  const float* b = (const float*)d_in[2];
  char* ws = (char*)d_ws;
  __half* Gx           = (__half*)(ws + GX_OFF);
  unsigned short* xb   = (unsigned short*)(ws + XB_OFF);   // becomes h ring
  unsigned short* Wh   = (unsigned short*)(ws + WH_OFF);
  unsigned short* Wx   = (unsigned short*)(ws + WX_OFF);
  unsigned* flags      = (unsigned*)(ws + FLG_OFF);
  float* out = (float*)d_out;

  // prep: bf16 conversions + zero flags (re-zeroed every call -> deterministic)
  k_convert_w<<<8192, 256, 0, stream>>>(W, Wh, Wx);
  k_convert_x<<<16384, 256, 0, stream>>>(x, xb);
  k_zero_wt<<<8, 256, 0, stream>>>(flags, 2048);

  // input projection for all timesteps (consumes xb)
  k_xgemm<<<dim3(128, 32), 256, 0, stream>>>(xb, Wx, Gx);

  // persistent recurrence (84608 B dynamic LDS > 64KB default -> raise cap)
  (void)hipFuncSetAttribute((const void*)k_lstm,
                            hipFuncAttributeMaxDynamicSharedMemorySize, 84608);
  k_lstm<<<128, 256, 84608, stream>>>(Wh, Gx, b, xb, out, flags);
}